// Round 22
// baseline (43.460 us; speedup 1.0000x reference)
//
#include <hip/hip_runtime.h>

#define BATCH 8
#define CIN   64
#define COUT  64
#define LEN   16384
#define KS    5
#define PADW  2
#define LP    (LEN + 2*PADW)
#define TTB   128            // cols per block (2 subtiles of 64, fused compute)
#define XROWS 104            // staged rows per subtile window
#define XM    14             // S0 = t0s - 14 => x idx of row r = t0s - 16 + r (16B aligned)

typedef __attribute__((ext_vector_type(8)))  short short8;
typedef __attribute__((ext_vector_type(4)))  float f32x4;

__device__ __forceinline__ unsigned short bf16r(float f) {
    unsigned u = __builtin_bit_cast(unsigned, f);
    u += 0x7FFF + ((u >> 16) & 1);          // RNE
    return (unsigned short)(u >> 16);
}
// fast pack: round-half-up both floats to bf16, pack into one u32 (1 v_perm)
__device__ __forceinline__ unsigned fpack(float a, float b) {
    unsigned ua = __builtin_bit_cast(unsigned, a) + 0x8000u;
    unsigned ub = __builtin_bit_cast(unsigned, b) + 0x8000u;
    return __builtin_amdgcn_perm(ub, ua, 0x07060302);   // [ub.b3 ub.b2 ua.b3 ua.b2]
}
__device__ __forceinline__ int reflmap(int s) {  // padded idx -> x idx
    return (s < PADW) ? (PADW - s) : ((s < LEN + PADW) ? (s - PADW) : (2*LEN - s));
}

// W (f32 [o][c][k]) -> bf16 A-frags for mfma_f32_16x16x32_bf16, K k-major
// (ck' = ktap*64 + c).  wf[((ot*10 + kk)*64 + lane)*8 + e]
__global__ void wfrag_kernel(const float* __restrict__ w, unsigned short* __restrict__ wf) {
    int el = blockIdx.x * 256 + threadIdx.x;          // 20480 total
    int e    = el & 7;
    int lane = (el >> 3) & 63;
    int kk   = (el >> 9) % 10;
    int ot   = el / 5120;
    int o    = ot * 16 + (lane & 15);
    int kg   = kk * 32 + ((lane >> 4) << 3) + e;      // ck' 0..319
    int ktap = kg >> 6;
    int c    = kg & 63;
    wf[el] = bf16r(w[(o * 64 + c) * 5 + ktap]);
}

__global__ __launch_bounds__(256, 6) void deform_mfma_kernel(
    const float* __restrict__ x, const float* __restrict__ offs,
    const unsigned short* __restrict__ wf, const float* __restrict__ bias,
    float* __restrict__ out)
{
    __shared__ __align__(16) unsigned short xtl[2][XROWS * 64];   // 2 x 13312 B

    const int tid = threadIdx.x;
    const int bid = blockIdx.x;
    const int bt  = (bid & 7) * 128 + (bid >> 3);    // XCD swizzle (1024 = 8*128)
    const int b   = bt >> 7;
    const int T0  = (bt & 127) * TTB;
    const int w   = tid >> 6;
    const int lane = tid & 63;
    const int pl  = lane & 15;
    const int s   = lane >> 4;

    const float* xb0 = x + (size_t)b * CIN * LEN;
    const unsigned short* wfl = wf + (size_t)lane * 8;

    // ---- preload offsets for both subtiles ----
    float of0[KS], of1[KS];
    {
        const int tcc = T0 + w * 16 + pl;
        #pragma unroll
        for (int k = 0; k < KS; ++k) of0[k] = offs[((size_t)(b * LEN + tcc)) * KS + k];
        #pragma unroll
        for (int k = 0; k < KS; ++k) of1[k] = offs[((size_t)(b * LEN + tcc + 64)) * KS + k];
    }

    float4 vA0[2], vA1[2], vB0[2], vB1[2];
    int stg_fast;

    // row r of subtile window = xp[S0+r] = x[t0s-16+r]; base 16B aligned.
#define STAGE_LOAD(t0s)                                                        \
    stg_fast = ((t0s) >= 16 && (t0s) + 88 <= LEN);                             \
    if (stg_fast) {                                                            \
        const float* src0 = xb0 + ((t0s) - 16);                                \
        _Pragma("unroll")                                                      \
        for (int rep = 0; rep < 2; ++rep) {                                    \
            int task = rep * 256 + tid;          /* 416 = 32 ch-pairs x 13 */  \
            if (task < 416) {                                                  \
                int c2 = task / 13, q = task - c2 * 13;                        \
                const float* p0 = src0 + (size_t)(2 * c2) * LEN + 8 * q;       \
                vA0[rep] = *(const float4*)p0;                                 \
                vA1[rep] = *(const float4*)(p0 + 4);                           \
                vB0[rep] = *(const float4*)(p0 + LEN);                         \
                vB1[rep] = *(const float4*)(p0 + LEN + 4);                     \
            }                                                                  \
        }                                                                      \
    }

#define STAGE_WRITE(dst, t0s)                                                  \
    if (stg_fast) {                                                            \
        _Pragma("unroll")                                                      \
        for (int rep = 0; rep < 2; ++rep) {                                    \
            int task = rep * 256 + tid;                                        \
            if (task < 416) {                                                  \
                int c2 = task / 13, q = task - c2 * 13;                        \
                float av[8] = {vA0[rep].x, vA0[rep].y, vA0[rep].z, vA0[rep].w, \
                               vA1[rep].x, vA1[rep].y, vA1[rep].z, vA1[rep].w};\
                float bv[8] = {vB0[rep].x, vB0[rep].y, vB0[rep].z, vB0[rep].w, \
                               vB1[rep].x, vB1[rep].y, vB1[rep].z, vB1[rep].w};\
                _Pragma("unroll")                                              \
                for (int i = 0; i < 8; ++i) {                                  \
                    int r = 8 * q + i;                                         \
                    *(unsigned*)((char*)(dst) + r * 128 +                      \
                        ((4 * c2) ^ ((r & 7) << 4))) = fpack(av[i], bv[i]);    \
                }                                                              \
            }                                                                  \
        }                                                                      \
    } else {                                                                   \
        const int S0e = (t0s) - XM;                                            \
        _Pragma("unroll")                                                      \
        for (int rep = 0; rep < 26; ++rep) {                                   \
            int idx = rep * 256 + tid;           /* 6656 = 104 x 64 */         \
            int r = idx >> 6, c = idx & 63;                                    \
            int sp = min(max(S0e + r, 0), LP - 1);                             \
            *(unsigned short*)((char*)(dst) + r * 128 +                        \
                ((2 * c) ^ ((r & 7) << 4))) = bf16r(xb0[(size_t)c * LEN + reflmap(sp)]); \
        }                                                                      \
    }

#define LERPW(dst, w0, w1, f)                                                  \
    {                                                                          \
        float g0a = __builtin_bit_cast(float, (w0) << 16);                     \
        float g1a = __builtin_bit_cast(float, (w1) << 16);                     \
        float g0b = __builtin_bit_cast(float, (w0) & 0xFFFF0000u);             \
        float g1b = __builtin_bit_cast(float, (w1) & 0xFFFF0000u);             \
        dst = fpack(fmaf(f, g1a - g0a, g0a), fmaf(f, g1b - g0b, g0b));         \
    }

    // gather one B-frag (fast path) from window XB at row array/frac
#define GATHF(pw, XB, R0A, FRA, k, mm)                                         \
    {                                                                          \
        const int r0 = R0A[k], r1 = r0 + 1;                                    \
        const float f = FRA[k];                                                \
        uint4 u0 = *(const uint4*)((const char*)(XB) + r0 * 128 + ((mm) ^ ((r0 & 7) << 4))); \
        uint4 u1 = *(const uint4*)((const char*)(XB) + r1 * 128 + ((mm) ^ ((r1 & 7) << 4))); \
        LERPW(pw.x, u0.x, u1.x, f) LERPW(pw.y, u0.y, u1.y, f)                  \
        LERPW(pw.z, u0.z, u1.z, f) LERPW(pw.w, u0.w, u1.w, f)                  \
    }

    // gather one B-frag (slow path, exact reflect from global)
#define GATHS(pw, I0A, FRA, k, m)                                              \
    {                                                                          \
        const float f = FRA[k];                                                \
        int j0 = reflmap(I0A[k]), j1 = reflmap(I0A[k] + 1);                    \
        const float* xc = xb0 + (size_t)((m) << 3) * LEN;                      \
        unsigned pv[4];                                                        \
        _Pragma("unroll")                                                      \
        for (int e = 0; e < 4; ++e) {                                          \
            float ga0 = xc[j0], ga1 = xc[j1];                                  \
            float lo = fmaf(f, ga1 - ga0, ga0);                                \
            float gb0 = xc[LEN + j0], gb1 = xc[LEN + j1];                      \
            float hi = fmaf(f, gb1 - gb0, gb0);                                \
            pv[e] = fpack(lo, hi);                                             \
            xc += 2 * LEN;                                                     \
        }                                                                      \
        pw = uint4{pv[0], pv[1], pv[2], pv[3]};                                \
    }

#define MFMA8(kk, pw0, pw1)                                                    \
    {                                                                          \
        short8 bv0 = __builtin_bit_cast(short8, pw0);                          \
        short8 bv1 = __builtin_bit_cast(short8, pw1);                          \
        short8 a0 = *(const short8*)&wfl[(0 * 10 + (kk)) * 512];               \
        short8 a1 = *(const short8*)&wfl[(1 * 10 + (kk)) * 512];               \
        short8 a2 = *(const short8*)&wfl[(2 * 10 + (kk)) * 512];               \
        short8 a3 = *(const short8*)&wfl[(3 * 10 + (kk)) * 512];               \
        __builtin_amdgcn_s_setprio(1);                                         \
        accA0 = __builtin_amdgcn_mfma_f32_16x16x32_bf16(a0, bv0, accA0, 0, 0, 0); \
        accB0 = __builtin_amdgcn_mfma_f32_16x16x32_bf16(a0, bv1, accB0, 0, 0, 0); \
        accA1 = __builtin_amdgcn_mfma_f32_16x16x32_bf16(a1, bv0, accA1, 0, 0, 0); \
        accB1 = __builtin_amdgcn_mfma_f32_16x16x32_bf16(a1, bv1, accB1, 0, 0, 0); \
        accA2 = __builtin_amdgcn_mfma_f32_16x16x32_bf16(a2, bv0, accA2, 0, 0, 0); \
        accB2 = __builtin_amdgcn_mfma_f32_16x16x32_bf16(a2, bv1, accB2, 0, 0, 0); \
        accA3 = __builtin_amdgcn_mfma_f32_16x16x32_bf16(a3, bv0, accA3, 0, 0, 0); \
        accB3 = __builtin_amdgcn_mfma_f32_16x16x32_bf16(a3, bv1, accB3, 0, 0, 0); \
        __builtin_amdgcn_s_setprio(0);                                         \
    }

#define FUSED(kk)                                                              \
    {                                                                          \
        const int k  = (kk) >> 1;                                              \
        const int mm = ((((kk) & 1) << 2) + s) * 16;                           \
        uint4 pw0, pw1;                                                        \
        GATHF(pw0, xtl[0], r00, fr0, k, mm)                                    \
        GATHF(pw1, xtl[1], r01, fr1, k, mm)                                    \
        MFMA8(kk, pw0, pw1)                                                    \
    }

#define CHECKED1(kk, pw, R0A, I0A, FRA, XB)                                    \
    {                                                                          \
        const int k = (kk) >> 1;                                               \
        const int m = (((kk) & 1) << 2) + s;                                   \
        if ((unsigned)R0A[k] <= (unsigned)(XROWS - 2)) {                       \
            GATHF(pw, XB, R0A, FRA, k, m * 16)                                 \
        } else {                                                               \
            GATHS(pw, I0A, FRA, k, m)                                          \
        }                                                                      \
    }

#define FUSEDC(kk)                                                             \
    {                                                                          \
        uint4 pw0, pw1;                                                        \
        CHECKED1(kk, pw0, r00, i00, fr0, xtl[0])                               \
        CHECKED1(kk, pw1, r01, i01, fr1, xtl[1])                               \
        MFMA8(kk, pw0, pw1)                                                    \
    }

    // ---- stage both windows, then one barrier ----
    STAGE_LOAD(T0);
    STAGE_WRITE(xtl[0], T0);
    STAGE_LOAD(T0 + 64);

    // ---- descriptors for both subtiles (hides under window-1 load latency) ----
    int i00[KS], i01[KS], r00[KS], r01[KS];
    float fr0[KS], fr1[KS];
    bool fastg = true;
    {
        const int tc0 = T0 + w * 16 + pl;
        #pragma unroll
        for (int k = 0; k < KS; ++k) {
            float T = (float)(tc0 + k) + of0[k];
            T = fminf(fmaxf(T, 0.0f), (float)(LP - 1));
            int i0 = (int)floorf(T);
            i0 = min(i0, LP - 2); i0 = max(i0, 0);
            i00[k] = i0; fr0[k] = T - (float)i0; r00[k] = i0 - (T0 - XM);
            fastg = fastg && ((unsigned)r00[k] <= (unsigned)(XROWS - 2));
        }
        #pragma unroll
        for (int k = 0; k < KS; ++k) {
            float T = (float)(tc0 + 64 + k) + of1[k];
            T = fminf(fmaxf(T, 0.0f), (float)(LP - 1));
            int i0 = (int)floorf(T);
            i0 = min(i0, LP - 2); i0 = max(i0, 0);
            i01[k] = i0; fr1[k] = T - (float)i0; r01[k] = i0 - (T0 + 64 - XM);
            fastg = fastg && ((unsigned)r01[k] <= (unsigned)(XROWS - 2));
        }
    }

    STAGE_WRITE(xtl[1], T0 + 64);
    __syncthreads();

    // ---- fused compute: 10 steps x {2 gathers, 4 A-loads, 8 MFMA} ----
    f32x4 accA0 = {}, accA1 = {}, accA2 = {}, accA3 = {};
    f32x4 accB0 = {}, accB1 = {}, accB2 = {}, accB3 = {};
    if (fastg) {
        FUSED(0) FUSED(1) FUSED(2) FUSED(3) FUSED(4)
        FUSED(5) FUSED(6) FUSED(7) FUSED(8) FUSED(9)
    } else {
        FUSEDC(0) FUSEDC(1) FUSEDC(2) FUSEDC(3) FUSEDC(4)
        FUSEDC(5) FUSEDC(6) FUSEDC(7) FUSEDC(8) FUSEDC(9)
    }

    // ---- epilogue: both subtiles; C/D col=pl, row=s*4+r ----
    {
        const int tc0 = T0 + w * 16 + pl;
        #pragma unroll
        for (int ot = 0; ot < 4; ++ot) {
            const f32x4 aA = (ot==0)?accA0:(ot==1)?accA1:(ot==2)?accA2:accA3;
            const f32x4 aB = (ot==0)?accB0:(ot==1)?accB1:(ot==2)?accB2:accB3;
            #pragma unroll
            for (int r = 0; r < 4; ++r) {
                int o = ot * 16 + s * 4 + r;
                float bvv = bias[o];
                float* op = out + ((size_t)(b * COUT + o)) * LEN + tc0;
                op[0]  = aA[r] + bvv;
                op[64] = aB[r] + bvv;
            }
        }
    }
#undef FUSEDC
#undef CHECKED1
#undef FUSED
#undef MFMA8
#undef GATHS
#undef GATHF
#undef LERPW
#undef STAGE_WRITE
#undef STAGE_LOAD
}

extern "C" void kernel_launch(void* const* d_in, const int* in_sizes, int n_in,
                              void* d_out, int out_size, void* d_ws, size_t ws_size,
                              hipStream_t stream) {
    const float* x    = (const float*)d_in[0];
    const float* offs = (const float*)d_in[1];
    const float* w    = (const float*)d_in[2];
    const float* bias = (const float*)d_in[3];
    float* out = (float*)d_out;
    unsigned short* wf = (unsigned short*)d_ws;   // 40960 B

    wfrag_kernel<<<80, 256, 0, stream>>>(w, wf);
    deform_mfma_kernel<<<BATCH * (LEN / TTB), 256, 0, stream>>>(x, offs, wf, bias, out);
}

// Round 23
// 31.289 us; speedup vs baseline: 1.3890x; 1.3890x over previous
//
#include <hip/hip_runtime.h>

#define BATCH 8
#define CIN   64
#define COUT  64
#define LEN   16384
#define KS    5
#define PADW  2
#define LP    (LEN + 2*PADW)
#define TTB   128            // cols per block (2 subtiles of 64, fused compute)
#define XROWS 104            // staged rows per subtile window
#define XM    14             // S0 = t0s - 14 => x idx of row r = t0s - 16 + r (16B aligned)

typedef __attribute__((ext_vector_type(8)))  short short8;
typedef __attribute__((ext_vector_type(4)))  float f32x4;

__device__ __forceinline__ unsigned short bf16r(float f) {
    unsigned u = __builtin_bit_cast(unsigned, f);
    u += 0x7FFF + ((u >> 16) & 1);          // RNE
    return (unsigned short)(u >> 16);
}
// fast pack: round-half-up both floats to bf16, pack into one u32 (1 v_perm)
__device__ __forceinline__ unsigned fpack(float a, float b) {
    unsigned ua = __builtin_bit_cast(unsigned, a) + 0x8000u;
    unsigned ub = __builtin_bit_cast(unsigned, b) + 0x8000u;
    return __builtin_amdgcn_perm(ub, ua, 0x07060302);   // [ub.b3 ub.b2 ua.b3 ua.b2]
}
__device__ __forceinline__ int reflmap(int s) {  // padded idx -> x idx
    return (s < PADW) ? (PADW - s) : ((s < LEN + PADW) ? (s - PADW) : (2*LEN - s));
}

// W (f32 [o][c][k]) -> bf16 A-frags for mfma_f32_16x16x32_bf16, K k-major
// (ck' = ktap*64 + c).  wf[((ot*10 + kk)*64 + lane)*8 + e]
__global__ void wfrag_kernel(const float* __restrict__ w, unsigned short* __restrict__ wf) {
    int el = blockIdx.x * 256 + threadIdx.x;          // 20480 total
    int e    = el & 7;
    int lane = (el >> 3) & 63;
    int kk   = (el >> 9) % 10;
    int ot   = el / 5120;
    int o    = ot * 16 + (lane & 15);
    int kg   = kk * 32 + ((lane >> 4) << 3) + e;      // ck' 0..319
    int ktap = kg >> 6;
    int c    = kg & 63;
    wf[el] = bf16r(w[(o * 64 + c) * 5 + ktap]);
}

__global__ __launch_bounds__(256, 4) void deform_mfma_kernel(
    const float* __restrict__ x, const float* __restrict__ offs,
    const unsigned short* __restrict__ wf, const float* __restrict__ bias,
    float* __restrict__ out)
{
    __shared__ __align__(16) unsigned short xtl[2][XROWS * 64];   // 2 x 13312 B

    const int tid = threadIdx.x;
    const int bid = blockIdx.x;
    const int bt  = (bid & 7) * 128 + (bid >> 3);    // XCD swizzle (1024 = 8*128)
    const int b   = bt >> 7;
    const int T0  = (bt & 127) * TTB;
    const int w   = tid >> 6;
    const int lane = tid & 63;
    const int pl  = lane & 15;
    const int s   = lane >> 4;

    const float* xb0 = x + (size_t)b * CIN * LEN;
    const unsigned short* wfl = wf + (size_t)lane * 8;

    // ---- preload offsets for both subtiles ----
    float of0[KS], of1[KS];
    {
        const int tcc = T0 + w * 16 + pl;
        #pragma unroll
        for (int k = 0; k < KS; ++k) of0[k] = offs[((size_t)(b * LEN + tcc)) * KS + k];
        #pragma unroll
        for (int k = 0; k < KS; ++k) of1[k] = offs[((size_t)(b * LEN + tcc + 64)) * KS + k];
    }

    float4 vA0[2], vA1[2], vB0[2], vB1[2];
    int stg_fast;

    // row r of subtile window = xp[S0+r] = x[t0s-16+r]; base 16B aligned.
    // task map c2 = task&31 (bank = c2 ^ (i<<2) -> all 32 banks per 32 lanes)
#define STAGE_LOAD(t0s)                                                        \
    stg_fast = ((t0s) >= 16 && (t0s) + 88 <= LEN);                             \
    if (stg_fast) {                                                            \
        const float* src0 = xb0 + ((t0s) - 16);                                \
        _Pragma("unroll")                                                      \
        for (int rep = 0; rep < 2; ++rep) {                                    \
            int task = rep * 256 + tid;          /* 416 = 32 c2 x 13 q */      \
            if (task < 416) {                                                  \
                int c2 = task & 31, q = task >> 5;                             \
                const float* p0 = src0 + (size_t)(2 * c2) * LEN + 8 * q;       \
                vA0[rep] = *(const float4*)p0;                                 \
                vA1[rep] = *(const float4*)(p0 + 4);                           \
                vB0[rep] = *(const float4*)(p0 + LEN);                         \
                vB1[rep] = *(const float4*)(p0 + LEN + 4);                     \
            }                                                                  \
        }                                                                      \
    }

#define STAGE_WRITE(dst, t0s)                                                  \
    if (stg_fast) {                                                            \
        _Pragma("unroll")                                                      \
        for (int rep = 0; rep < 2; ++rep) {                                    \
            int task = rep * 256 + tid;                                        \
            if (task < 416) {                                                  \
                int c2 = task & 31, q = task >> 5;                             \
                float av[8] = {vA0[rep].x, vA0[rep].y, vA0[rep].z, vA0[rep].w, \
                               vA1[rep].x, vA1[rep].y, vA1[rep].z, vA1[rep].w};\
                float bv[8] = {vB0[rep].x, vB0[rep].y, vB0[rep].z, vB0[rep].w, \
                               vB1[rep].x, vB1[rep].y, vB1[rep].z, vB1[rep].w};\
                _Pragma("unroll")                                              \
                for (int i = 0; i < 8; ++i) {                                  \
                    int r = 8 * q + i;                                         \
                    *(unsigned*)((char*)(dst) + r * 128 +                      \
                        ((4 * c2) ^ ((r & 7) << 4))) = fpack(av[i], bv[i]);    \
                }                                                              \
            }                                                                  \
        }                                                                      \
    } else {                                                                   \
        const int S0e = (t0s) - XM;                                            \
        _Pragma("unroll")                                                      \
        for (int rep = 0; rep < 26; ++rep) {                                   \
            int idx = rep * 256 + tid;           /* 6656 = 104 x 64 */         \
            int r = idx >> 6, c = idx & 63;                                    \
            int sp = min(max(S0e + r, 0), LP - 1);                             \
            *(unsigned short*)((char*)(dst) + r * 128 +                        \
                ((2 * c) ^ ((r & 7) << 4))) = bf16r(xb0[(size_t)c * LEN + reflmap(sp)]); \
        }                                                                      \
    }

#define LERPW(dst, w0, w1, f)                                                  \
    {                                                                          \
        float g0a = __builtin_bit_cast(float, (w0) << 16);                     \
        float g1a = __builtin_bit_cast(float, (w1) << 16);                     \
        float g0b = __builtin_bit_cast(float, (w0) & 0xFFFF0000u);             \
        float g1b = __builtin_bit_cast(float, (w1) & 0xFFFF0000u);             \
        dst = fpack(fmaf(f, g1a - g0a, g0a), fmaf(f, g1b - g0b, g0b));         \
    }

    // gather one B-frag (fast path) from window XB at row array/frac
#define GATHF(pw, XB, R0A, FRA, k, mm)                                         \
    {                                                                          \
        const int r0 = R0A[k], r1 = r0 + 1;                                    \
        const float f = FRA[k];                                                \
        uint4 u0 = *(const uint4*)((const char*)(XB) + r0 * 128 + ((mm) ^ ((r0 & 7) << 4))); \
        uint4 u1 = *(const uint4*)((const char*)(XB) + r1 * 128 + ((mm) ^ ((r1 & 7) << 4))); \
        LERPW(pw.x, u0.x, u1.x, f) LERPW(pw.y, u0.y, u1.y, f)                  \
        LERPW(pw.z, u0.z, u1.z, f) LERPW(pw.w, u0.w, u1.w, f)                  \
    }

    // gather one B-frag (slow path, exact reflect from global)
#define GATHS(pw, I0A, FRA, k, m)                                              \
    {                                                                          \
        const float f = FRA[k];                                                \
        int j0 = reflmap(I0A[k]), j1 = reflmap(I0A[k] + 1);                    \
        const float* xc = xb0 + (size_t)((m) << 3) * LEN;                      \
        unsigned pv[4];                                                        \
        _Pragma("unroll")                                                      \
        for (int e = 0; e < 4; ++e) {                                          \
            float ga0 = xc[j0], ga1 = xc[j1];                                  \
            float lo = fmaf(f, ga1 - ga0, ga0);                                \
            float gb0 = xc[LEN + j0], gb1 = xc[LEN + j1];                      \
            float hi = fmaf(f, gb1 - gb0, gb0);                                \
            pv[e] = fpack(lo, hi);                                             \
            xc += 2 * LEN;                                                     \
        }                                                                      \
        pw = uint4{pv[0], pv[1], pv[2], pv[3]};                                \
    }

#define MFMA8(kk, pw0, pw1)                                                    \
    {                                                                          \
        short8 bv0 = __builtin_bit_cast(short8, pw0);                          \
        short8 bv1 = __builtin_bit_cast(short8, pw1);                          \
        short8 a0 = *(const short8*)&wfl[(0 * 10 + (kk)) * 512];               \
        short8 a1 = *(const short8*)&wfl[(1 * 10 + (kk)) * 512];               \
        short8 a2 = *(const short8*)&wfl[(2 * 10 + (kk)) * 512];               \
        short8 a3 = *(const short8*)&wfl[(3 * 10 + (kk)) * 512];               \
        __builtin_amdgcn_s_setprio(1);                                         \
        accA0 = __builtin_amdgcn_mfma_f32_16x16x32_bf16(a0, bv0, accA0, 0, 0, 0); \
        accB0 = __builtin_amdgcn_mfma_f32_16x16x32_bf16(a0, bv1, accB0, 0, 0, 0); \
        accA1 = __builtin_amdgcn_mfma_f32_16x16x32_bf16(a1, bv0, accA1, 0, 0, 0); \
        accB1 = __builtin_amdgcn_mfma_f32_16x16x32_bf16(a1, bv1, accB1, 0, 0, 0); \
        accA2 = __builtin_amdgcn_mfma_f32_16x16x32_bf16(a2, bv0, accA2, 0, 0, 0); \
        accB2 = __builtin_amdgcn_mfma_f32_16x16x32_bf16(a2, bv1, accB2, 0, 0, 0); \
        accA3 = __builtin_amdgcn_mfma_f32_16x16x32_bf16(a3, bv0, accA3, 0, 0, 0); \
        accB3 = __builtin_amdgcn_mfma_f32_16x16x32_bf16(a3, bv1, accB3, 0, 0, 0); \
        __builtin_amdgcn_s_setprio(0);                                         \
    }

#define FUSED(kk)                                                              \
    {                                                                          \
        const int k  = (kk) >> 1;                                              \
        const int mm = ((((kk) & 1) << 2) + s) * 16;                           \
        uint4 pw0, pw1;                                                        \
        GATHF(pw0, xtl[0], r00, fr0, k, mm)                                    \
        GATHF(pw1, xtl[1], r01, fr1, k, mm)                                    \
        MFMA8(kk, pw0, pw1)                                                    \
    }

#define CHECKED1(kk, pw, R0A, I0A, FRA, XB)                                    \
    {                                                                          \
        const int k = (kk) >> 1;                                               \
        const int m = (((kk) & 1) << 2) + s;                                   \
        if ((unsigned)R0A[k] <= (unsigned)(XROWS - 2)) {                       \
            GATHF(pw, XB, R0A, FRA, k, m * 16)                                 \
        } else {                                                               \
            GATHS(pw, I0A, FRA, k, m)                                          \
        }                                                                      \
    }

#define FUSEDC(kk)                                                             \
    {                                                                          \
        uint4 pw0, pw1;                                                        \
        CHECKED1(kk, pw0, r00, i00, fr0, xtl[0])                               \
        CHECKED1(kk, pw1, r01, i01, fr1, xtl[1])                               \
        MFMA8(kk, pw0, pw1)                                                    \
    }

    // ---- stage both windows, then one barrier ----
    STAGE_LOAD(T0);
    STAGE_WRITE(xtl[0], T0);
    STAGE_LOAD(T0 + 64);

    // ---- descriptors for both subtiles (hides under window-1 load latency) ----
    int i00[KS], i01[KS], r00[KS], r01[KS];
    float fr0[KS], fr1[KS];
    bool fastg = true;
    {
        const int tc0 = T0 + w * 16 + pl;
        #pragma unroll
        for (int k = 0; k < KS; ++k) {
            float T = (float)(tc0 + k) + of0[k];
            T = fminf(fmaxf(T, 0.0f), (float)(LP - 1));
            int i0 = (int)floorf(T);
            i0 = min(i0, LP - 2); i0 = max(i0, 0);
            i00[k] = i0; fr0[k] = T - (float)i0; r00[k] = i0 - (T0 - XM);
            fastg = fastg && ((unsigned)r00[k] <= (unsigned)(XROWS - 2));
        }
        #pragma unroll
        for (int k = 0; k < KS; ++k) {
            float T = (float)(tc0 + 64 + k) + of1[k];
            T = fminf(fmaxf(T, 0.0f), (float)(LP - 1));
            int i0 = (int)floorf(T);
            i0 = min(i0, LP - 2); i0 = max(i0, 0);
            i01[k] = i0; fr1[k] = T - (float)i0; r01[k] = i0 - (T0 + 64 - XM);
            fastg = fastg && ((unsigned)r01[k] <= (unsigned)(XROWS - 2));
        }
    }

    STAGE_WRITE(xtl[1], T0 + 64);
    __syncthreads();

    // ---- fused compute: 10 steps x {2 gathers, 4 A-loads, 8 MFMA} ----
    f32x4 accA0 = {}, accA1 = {}, accA2 = {}, accA3 = {};
    f32x4 accB0 = {}, accB1 = {}, accB2 = {}, accB3 = {};
    if (fastg) {
        FUSED(0) FUSED(1) FUSED(2) FUSED(3) FUSED(4)
        FUSED(5) FUSED(6) FUSED(7) FUSED(8) FUSED(9)
    } else {
        FUSEDC(0) FUSEDC(1) FUSEDC(2) FUSEDC(3) FUSEDC(4)
        FUSEDC(5) FUSEDC(6) FUSEDC(7) FUSEDC(8) FUSEDC(9)
    }

    // ---- epilogue: both subtiles; C/D col=pl, row=s*4+r ----
    {
        const int tc0 = T0 + w * 16 + pl;
        #pragma unroll
        for (int ot = 0; ot < 4; ++ot) {
            const f32x4 aA = (ot==0)?accA0:(ot==1)?accA1:(ot==2)?accA2:accA3;
            const f32x4 aB = (ot==0)?accB0:(ot==1)?accB1:(ot==2)?accB2:accB3;
            #pragma unroll
            for (int r = 0; r < 4; ++r) {
                int o = ot * 16 + s * 4 + r;
                float bvv = bias[o];
                float* op = out + ((size_t)(b * COUT + o)) * LEN + tc0;
                op[0]  = aA[r] + bvv;
                op[64] = aB[r] + bvv;
            }
        }
    }
#undef FUSEDC
#undef CHECKED1
#undef FUSED
#undef MFMA8
#undef GATHS
#undef GATHF
#undef LERPW
#undef STAGE_WRITE
#undef STAGE_LOAD
}

extern "C" void kernel_launch(void* const* d_in, const int* in_sizes, int n_in,
                              void* d_out, int out_size, void* d_ws, size_t ws_size,
                              hipStream_t stream) {
    const float* x    = (const float*)d_in[0];
    const float* offs = (const float*)d_in[1];
    const float* w    = (const float*)d_in[2];
    const float* bias = (const float*)d_in[3];
    float* out = (float*)d_out;
    unsigned short* wf = (unsigned short*)d_ws;   // 40960 B

    wfrag_kernel<<<80, 256, 0, stream>>>(w, wf);
    deform_mfma_kernel<<<BATCH * (LEN / TTB), 256, 0, stream>>>(x, offs, wf, bias, out);
}